// Round 15
// baseline (96.826 us; speedup 1.0000x reference)
//
#include <hip/hip_runtime.h>

typedef short bf16x8 __attribute__((ext_vector_type(8)));
typedef float f32x16 __attribute__((ext_vector_type(16)));

#define BIG_F 1e10f
constexpr int B = 16;
constexpr int N = 4096;
constexpr int COLS = 512;           // staged cols per block
constexpr int NCB = N / COLS;       // 8
constexpr int JOBS = 4;             // 128-row jobs per staged slice
constexpr int SUBROWS = 512;        // rows per block
constexpr int NSUB = N / SUBROWS;   // 8
// per-direction partials: [B][NCB][2 ssets][N]
constexpr size_t PARTSZ = (size_t)B * NCB * 2 * N;   // 4 MB of floats

// truncating bf16 hi/lo split: v ~= hi + lo
__device__ __forceinline__ void split(float v, unsigned& h, unsigned& l) {
    unsigned hb = __float_as_uint(v) & 0xFFFF0000u;
    h = hb >> 16;
    float r = v - __uint_as_float(hb);
    l = __float_as_uint(r) >> 16;
}

__device__ __forceinline__ float min3f(float a, float b, float c) {
    return fminf(fminf(a, b), c);   // fuses to v_min3_f32
}

__device__ __forceinline__ float4 min4(float4 a, float4 b) {
    return make_float4(fminf(a.x, b.x), fminf(a.y, b.y),
                       fminf(a.z, b.z), fminf(a.w, b.w));
}

// VALU-pipe cross-lane min via DPP (no ds-op). Validated exact (R8-R14).
#define DPP_MIN(v, ctrl)                                                      \
    v = fminf(v, __int_as_float(__builtin_amdgcn_update_dpp(                  \
            __float_as_int(v), __float_as_int(v), (ctrl), 0xF, 0xF, false)))

// Fragment styles (bit-identical across both MFMA operand roles — R14):
// ROWstyle(v, s=|v|^2+madd): k = [ah0..2,ah0..2,al0..2, sh,sl,1,1]  (a=-2v)
// COLstyle(v, s=|v|^2+madd): k = [vh0..2,vl0..2,vh0..2,vl0..2, 1,1, sh,sl]
__device__ __forceinline__ void rowstyle(float v0, float v1, float v2,
                                         float madd, uint4& w0, uint4& w1) {
    float s = fmaf(v2, v2, fmaf(v1, v1, v0 * v0)) + madd;
    unsigned h0, l0, h1, l1, h2, l2, sh, sl;
    split(-2.0f * v0, h0, l0);
    split(-2.0f * v1, h1, l1);
    split(-2.0f * v2, h2, l2);
    split(s, sh, sl);
    w0 = make_uint4(h0 | (h1 << 16), h2 | (h0 << 16), h1 | (h2 << 16), l0 | (l1 << 16));
    w1 = make_uint4(l2 | (l0 << 16), l1 | (l2 << 16), sh | (sl << 16), 0x3F803F80u);
}
__device__ __forceinline__ void colstyle(float v0, float v1, float v2,
                                         float madd, uint4& w0, uint4& w1) {
    float s = fmaf(v2, v2, fmaf(v1, v1, v0 * v0)) + madd;
    unsigned h0, l0, h1, l1, h2, l2, sh, sl;
    split(v0, h0, l0);
    split(v1, h1, l1);
    split(v2, h2, l2);
    split(s, sh, sl);
    unsigned u0 = h0 | (h1 << 16), u1 = h2 | (l0 << 16), u2 = l1 | (l2 << 16);
    w0 = make_uint4(u0, u1, u2, u0);
    w1 = make_uint4(u1, u2, 0x3F803F80u, sh | (sl << 16));
}

// Pack each point ONCE into two global fragment tables (R5 validated pattern):
// Txrow = rowstyle(x)  — A-side of dir0, B-side of dir1
// Tycol = colstyle(y)  — B-side of dir0, A-side of dir1
__global__ __launch_bounds__(256) void pack_kernel(
    const float* __restrict__ x, const float* __restrict__ y,
    const int* __restrict__ mask,
    uint4* __restrict__ Txrow, uint4* __restrict__ Tycol,
    float* __restrict__ out)
{
    const int idx = blockIdx.x * 256 + threadIdx.x;   // 65536 = 16*4096
    if (idx == 0) out[0] = 0.0f;                      // finalize accumulates later
    const int b  = idx >> 12;
    const int pt = idx & (N - 1);
    const float* xb = x + (size_t)b * 3 * N;
    const float* yb = y + (size_t)b * 3 * N;
    const float madd = mask[b * N + pt] ? 0.0f : BIG_F;
    uint4 w0, w1;
    rowstyle(xb[pt], xb[N + pt], xb[2 * N + pt], madd, w0, w1);
    Txrow[(size_t)(b * 2 + 0) * N + pt] = w0;
    Txrow[(size_t)(b * 2 + 1) * N + pt] = w1;
    colstyle(yb[pt], yb[N + pt], yb[2 * N + pt], madd, w0, w1);
    Tycol[(size_t)(b * 2 + 0) * N + pt] = w0;
    Tycol[(size_t)(b * 2 + 1) * N + pt] = w1;
}

// R15: occupancy-first chamfer. 14 rounds showed only resident-wave count
// moves this kernel (R11 +waves = win; R10/R13 micro-opts = null; R14 +work
// at fixed waves = proportional loss). This version: (256,6) -> 85-reg
// budget, 6 waves/SIMD (2x R13); LDS 16 KB only (symmetric 2-dir scheme,
// row-min only -> no colbuf/vmin16/second barrier); A-frag = 1 global load
// from pre-packed table (no buildA VALU); B-stage = pure copy. Live set ~68
// regs (C-pair 32 + rm 16 + afr 4 + bf 8 + addr). Spill tripwire: chamfer
// WRITE_SIZE must stay ~8 MB.
__global__ __launch_bounds__(256, 6) void chamfer_mfma(
    const uint4* __restrict__ Txrow, const uint4* __restrict__ Tycol,
    float* __restrict__ part)      // [2][B][NCB][2][N]: dir0=mins2, dir1=mins1
{
    const int blk  = blockIdx.x;    // 0..2047
    const int dir  = blk & 1;
    const int rest = blk >> 1;
    const int b    = rest >> 6;
    const int cb   = (rest >> 3) & 7;
    const int sub  = rest & 7;
    const int t    = threadIdx.x;

    __shared__ __align__(16) unsigned short Bpack[2][COLS][8];  // 16 KB

    const uint4* rowT = dir ? Tycol : Txrow;   // A-frag table (per-lane rows)
    const uint4* colT = dir ? Txrow : Tycol;   // B-stage table (staged cols)

    // ---- stage this block's 512-col slice: pure copy, 4 uint4/thread ----
    uint4* Bl = (uint4*)&Bpack[0][0][0];
    const uint4* Bg = colT + (size_t)b * 2 * N + cb * COLS;
#pragma unroll
    for (int k = 0; k < 4; ++k) {
        int i = t + k * 256;                  // i>>9 = khalf, i&511 = col
        Bl[i] = Bg[(size_t)(i >> 9) * N + (i & 511)];
    }

    const int w    = t >> 6;    // wave 0..3
    const int L    = t & 63;
    const int half = L >> 5;    // k-half 0/1
    const int lc   = L & 31;

    __syncthreads();

    const unsigned short* Bb = &Bpack[half][lc][0];  // +p*512 shorts = col p*64+lc
    const f32x16 z16 = {0.f,0.f,0.f,0.f,0.f,0.f,0.f,0.f,
                        0.f,0.f,0.f,0.f,0.f,0.f,0.f,0.f};
    float* pbase = part + (size_t)dir * PARTSZ;

#pragma unroll 1
    for (int jj = 0; jj < JOBS; ++jj) {
        const int rowbase = sub * SUBROWS + jj * 128;
        // A fragment: one 16B global load from the pre-packed table
        uint4 av = rowT[(size_t)(b * 2 + half) * N + rowbase + w * 32 + lc];
        bf16x8 afr = *(bf16x8*)&av;

        float rm[16];
#pragma unroll
        for (int r = 0; r < 16; ++r) rm[r] = 1e30f;

#pragma unroll 1
        for (int p = 0; p < 8; ++p) {          // 8 col-pairs of 32 = 512 cols
            bf16x8 bf0 = *(const bf16x8*)(Bb + p * 512);
            bf16x8 bf1 = *(const bf16x8*)(Bb + p * 512 + 256);
            f32x16 C0 = __builtin_amdgcn_mfma_f32_32x32x16_bf16(afr, bf0, z16, 0, 0, 0);
            f32x16 C1 = __builtin_amdgcn_mfma_f32_32x32x16_bf16(afr, bf1, z16, 0, 0, 0);
            // C[r]: row = rowbase + w*32 + (r&3)+8*(r>>2)+4*half, col = p*64(+32)+lc
#pragma unroll
            for (int r = 0; r < 16; ++r) rm[r] = min3f(rm[r], C0[r], C1[r]);
        }

        // ---- row-min over each 16-lane group, entirely on the VALU pipe ----
#pragma unroll
        for (int r = 0; r < 16; ++r) {
            DPP_MIN(rm[r], 0xB1);    // quad_perm xor1
            DPP_MIN(rm[r], 0x4E);    // quad_perm xor2
            DPP_MIN(rm[r], 0x124);   // row_ror:4
            DPP_MIN(rm[r], 0x128);   // row_ror:8
        }
        if ((lc & 15) == 0) {        // lanes 0,16,32,48: (half, col-subset)
            int sset = lc >> 4;
            float* rp = pbase + (((size_t)(b * NCB + cb)) * 2 + sset) * N
                      + rowbase + w * 32 + half * 4;
            *(float4*)(rp +  0) = make_float4(rm[0],  rm[1],  rm[2],  rm[3]);
            *(float4*)(rp +  8) = make_float4(rm[4],  rm[5],  rm[6],  rm[7]);
            *(float4*)(rp + 16) = make_float4(rm[8],  rm[9],  rm[10], rm[11]);
            *(float4*)(rp + 24) = make_float4(rm[12], rm[13], rm[14], rm[15]);
        }
    }
}

__global__ __launch_bounds__(256) void finalize_kernel(
    const int* __restrict__ mask,
    const float* __restrict__ part,
    float* __restrict__ out)
{
    const int b = blockIdx.x & 15;
    const int q = blockIdx.x >> 4;   // quarter 0..3
    const int t = threadIdx.x;
    const int* mrow = mask + b * N;

    int cnt = 0;
    for (int i = t; i < N / 4; i += 256) {
        int4 mk = ((const int4*)mrow)[i];
        cnt += mk.x + mk.y + mk.z + mk.w;
    }

    const int p0 = q * 1024 + t * 4;
    const float* d0 = part + (size_t)b * NCB * 2 * N + p0;            // mins2
    const float* d1 = part + PARTSZ + (size_t)b * NCB * 2 * N + p0;   // mins1

    float4 rn = *(const float4*)d0;
    float4 mn = *(const float4*)d1;
#pragma unroll 8
    for (int pb = 1; pb < NCB * 2; ++pb) {
        rn = min4(rn, *(const float4*)(d0 + (size_t)pb * N));
        mn = min4(mn, *(const float4*)(d1 + (size_t)pb * N));
    }
    int4 mk = *(const int4*)(mrow + p0);
    float s = (mk.x ? (mn.x + rn.x) : 0.f) + (mk.y ? (mn.y + rn.y) : 0.f)
            + (mk.z ? (mn.z + rn.z) : 0.f) + (mk.w ? (mn.w + rn.w) : 0.f);

    for (int off = 32; off > 0; off >>= 1) {
        s   += __shfl_down(s, off);
        cnt += __shfl_down(cnt, off);
    }
    __shared__ float rs[4];
    __shared__ int   rc[4];
    const int wv = t >> 6;
    if ((t & 63) == 0) { rs[wv] = s; rc[wv] = cnt; }
    __syncthreads();
    if (t == 0) {
        float S = rs[0] + rs[1] + rs[2] + rs[3];
        float C = (float)(rc[0] + rc[1] + rc[2] + rc[3]);
        atomicAdd(out, (S / C) * (1.0f / 16.0f));
    }
}

extern "C" void kernel_launch(void* const* d_in, const int* in_sizes, int n_in,
                              void* d_out, int out_size, void* d_ws, size_t ws_size,
                              hipStream_t stream) {
    const float* x    = (const float*)d_in[0];
    const float* y    = (const float*)d_in[1];
    const int*   mask = (const int*)d_in[2];

    uint4* Txrow = (uint4*)d_ws;                          // B*2*N uint4 = 2 MB
    uint4* Tycol = Txrow + (size_t)B * 2 * N;             // 2 MB
    float* part  = (float*)(Tycol + (size_t)B * 2 * N);   // 2*PARTSZ = 8 MB

    pack_kernel<<<dim3(B * N / 256), 256, 0, stream>>>(
        x, y, mask, Txrow, Tycol, (float*)d_out);
    chamfer_mfma<<<dim3(2 * B * NCB * NSUB), 256, 0, stream>>>(
        Txrow, Tycol, part);
    finalize_kernel<<<dim3(64), 256, 0, stream>>>(
        mask, part, (float*)d_out);
}